// Round 13
// baseline (2939.481 us; speedup 1.0000x reference)
//
#include <hip/hip_runtime.h>

#define BB 4
#define NN 8192
#define SS 2048
#define KK 16

typedef float v2f __attribute__((ext_vector_type(2)));

// ---------------- FPS: 256 thr (4 waves), 32 pts/thread reg-pinned, 2 barriers, u32 atomicMin ----------------
// Same per-SIMD VALU issue as 512-thr variant, half the barrier participants.
#define FTH 256
#define FPT (NN/FTH)  // 32 points per thread
__global__ __launch_bounds__(FTH, 1) void fps_kernel(
    const float* __restrict__ xyz,   // [B,3,N]
    float* __restrict__ out_newxyz,  // [B,3,S]
    float* __restrict__ nxt)         // [B,S,3]
{
  #pragma clang fp contract(off)
  const int b = blockIdx.x;
  const int tid = threadIdx.x;
  const int wave = tid >> 6;
  const int lane = tid & 63;
  const float* xb = xyz + b*3*NN;
  __shared__ __align__(16) float4 sxyz[NN];         // 128 KB packed xyz copy
  __shared__ __align__(16) float smax[4];
  __shared__ unsigned gidx_slot[2];
  __shared__ int smi[SS];                           // winning-index history (8 KB)
  v2f px[FPT/2], py[FPT/2], pz[FPT/2], dist[FPT/2];
  #pragma unroll
  for (int j = 0; j < FPT; ++j) {
    int i = tid + j*FTH;
    float x = xb[i], y = xb[NN+i], z = xb[2*NN+i];
    asm volatile("" : "+v"(x), "+v"(y), "+v"(z));   // pin: forbid remat/reload
    ((float*)px)[j] = x; ((float*)py)[j] = y; ((float*)pz)[j] = z;
    ((float*)dist)[j] = 1e10f;
    sxyz[i] = make_float4(x, y, z, 0.0f);
  }
  if (tid == 0) { smi[0] = 0; gidx_slot[0] = 0xFFFFFFFFu; gidx_slot[1] = 0xFFFFFFFFu; }
  float cx = xb[0], cy = xb[NN], cz = xb[2*NN];
  __syncthreads();
  for (int it = 1; it < SS; ++it) {
    const int buf = it & 1;
    v2f cx2 = {cx, cx}, cy2 = {cy, cy}, cz2 = {cz, cz};
    v2f vmax = {-1.0f, -1.0f};
    #pragma unroll
    for (int j = 0; j < FPT/2; ++j) {
      // packed fp32: per-element arithmetic identical to scalar (contract off)
      v2f dx = px[j] - cx2, dy = py[j] - cy2, dz = pz[j] - cz2;
      v2f d = dx*dx + dy*dy;
      d = d + dz*dz;
      v2f nd = __builtin_elementwise_min(dist[j], d);
      dist[j] = nd;
      vmax = __builtin_elementwise_max(vmax, nd);
    }
    float mloc = fmaxf(vmax.x, vmax.y);
    // wave-level value-only max via DPP (identity 0 fill is safe: values >= 0)
    float m = mloc;
    #define FPS_DPP(ctrl) { \
      float s = __int_as_float(__builtin_amdgcn_update_dpp(0, __float_as_int(m), ctrl, 0xf, 0xf, true)); \
      m = fmaxf(m, s); }
    FPS_DPP(0x111)  // row_shr:1
    FPS_DPP(0x112)  // row_shr:2
    FPS_DPP(0x114)  // row_shr:4
    FPS_DPP(0x118)  // row_shr:8
    FPS_DPP(0x142)  // row_bcast:15
    FPS_DPP(0x143)  // row_bcast:31
    #undef FPS_DPP
    if (lane == 63) smax[wave] = m;
    __syncthreads();
    if (tid == 0) gidx_slot[1 - buf] = 0xFFFFFFFFu;   // reset buffer for next iteration
    float4 s0 = *(const float4*)smax;                  // 4 waves -> one b128 read
    float M = fmaxf(fmaxf(s0.x, s0.y), fmaxf(s0.z, s0.w));
    if (mloc == M) {
      // exact bit-equality: max propagates one of its inputs.
      // descending j, .y before .x -> smallest matching index in this thread
      int idx = 0x7FFFFFFF;
      #pragma unroll
      for (int j = FPT/2 - 1; j >= 0; --j) {
        if (dist[j].y == M) idx = tid + (2*j+1)*FTH;
        if (dist[j].x == M) idx = tid + (2*j)*FTH;
      }
      atomicMin(&gidx_slot[buf], (unsigned)idx);      // ties -> smallest index (np argmax)
    }
    __syncthreads();
    int mi = (int)gidx_slot[buf];
    if (tid == 0) smi[it] = mi;
    float4 c = sxyz[mi];                              // one ds_read_b128
    cx = c.x; cy = c.y; cz = c.z;
  }
  __syncthreads();
  // epilogue: write sampled coords coalesced, outside the serial loop
  for (int it = tid; it < SS; it += FTH) {
    int mi = smi[it];
    float4 c = sxyz[mi];
    out_newxyz[(b*3+0)*SS + it] = c.x;
    out_newxyz[(b*3+1)*SS + it] = c.y;
    out_newxyz[(b*3+2)*SS + it] = c.z;
    nxt[(b*SS+it)*3+0] = c.x; nxt[(b*SS+it)*3+1] = c.y; nxt[(b*SS+it)*3+2] = c.z;
  }
}

// ---------------- KNN fused: blocks [0,128) -> knn vs xyz (Nc=NN); [128,256) -> self-knn (Nc=SS) ----------------
#define TILE 2048
#define KTH 256
__global__ __launch_bounds__(KTH) void knn_kernel(
    const float* __restrict__ query_t, // [B,S,3]
    const float* __restrict__ cand1,   // [B,3,NN]
    const float* __restrict__ cand2,   // [B,3,SS]
    int* __restrict__ out1,            // [B,S,K]
    int* __restrict__ out2)            // [B,S,K]
{
  #pragma clang fp contract(off)
  __shared__ float4 sc[TILE];            // 32 KB
  __shared__ float  smd[4*64*17];        // per-wave top-16 dists (pad 17)
  __shared__ int    smj[4*64*17];        // per-wave top-16 idxs
  const int blocksPerB = SS/64;          // 32
  const int half = blockIdx.x >> 7;      // 0: vs xyz, 1: self
  const int blk = blockIdx.x & 127;
  const float* cand = half ? cand2 : cand1;
  const int Nc = half ? SS : NN;
  int* outidx = half ? out2 : out1;
  const int b = blk / blocksPerB;
  const int q0 = (blk % blocksPerB)*64;
  const int wave = threadIdx.x >> 6, lane = threadIdx.x & 63;
  const int s = q0 + lane;
  const float qx = query_t[(b*SS+s)*3+0];
  const float qy = query_t[(b*SS+s)*3+1];
  const float qz = query_t[(b*SS+s)*3+2];
  float sq = qx*qx + qy*qy; sq = sq + qz*qz;
  float d16[16]; int i16[16];
  #pragma unroll
  for (int j = 0; j < 16; ++j) { d16[j] = 1e30f; i16[j] = 0x7FFFFFFF; }
  const float* cb = cand + b*3*Nc;
  const int QL = TILE/4;
  for (int base = 0; base < Nc; base += TILE) {
    __syncthreads();
    for (int j = threadIdx.x; j < TILE; j += KTH) {
      float x = cb[base+j], y = cb[Nc+base+j], z = cb[2*Nc+base+j];
      float pp = x*x + y*y; pp = pp + z*z;
      sc[j] = make_float4(x, y, z, pp);
    }
    __syncthreads();
    const int lo = wave*QL, hi = lo + QL;
    for (int j = lo; j < hi; ++j) {
      float4 c = sc[j];
      float qp = qx*c.x + qy*c.y; qp = qp + qz*c.z;
      float d2 = (sq + c.w) - 2.0f*qp;
      if (d2 < d16[15]) {
        d16[15] = d2; i16[15] = base + j;
        #pragma unroll
        for (int t = 15; t > 0; --t) {
          if (d16[t] < d16[t-1]) {
            float td = d16[t]; d16[t] = d16[t-1]; d16[t-1] = td;
            int   ti = i16[t]; i16[t] = i16[t-1]; i16[t-1] = ti;
          }
        }
      }
    }
  }
  const int off = (wave*64 + lane)*17;
  #pragma unroll
  for (int j = 0; j < 16; ++j) { smd[off+j] = d16[j]; smj[off+j] = i16[j]; }
  __syncthreads();
  if (wave == 0) {
    // 4-way stable merge: tie-break on smaller index = stable lax.top_k semantics
    int p[4] = {0,0,0,0};
    for (int o = 0; o < 16; ++o) {
      float bd = 3e38f; int bi = 0x7FFFFFFF, bw = 0;
      #pragma unroll
      for (int w = 0; w < 4; ++w) {
        float d = smd[(w*64+lane)*17 + p[w]];
        int   i = smj[(w*64+lane)*17 + p[w]];
        if (d < bd || (d == bd && i < bi)) { bd = d; bi = i; bw = w; }
      }
      p[bw]++;
      outidx[(b*SS+s)*KK + o] = bi;
    }
  }
}

// ---------------- Transition-down conv + stats + max over K ----------------
__global__ __launch_bounds__(128) void td_kernel(
    const float* __restrict__ points,  // [B,64,N]
    const float* __restrict__ xyz,     // [B,3,N]
    const float* __restrict__ newxyz,  // [B,3,S]
    const int* __restrict__ gidx,      // [B,S,K]
    const float* __restrict__ td_w,    // [128,67]
    const float* __restrict__ td_b,    // [128]
    float* __restrict__ ymax,          // [B*S,128]
    float* __restrict__ psum,          // [B*S,128]
    float* __restrict__ psq)
{
  const int bs = blockIdx.x;
  const int b = bs >> 11, s = bs & (SS-1);
  const int t = threadIdx.x;
  __shared__ int gi[KK];
  __shared__ float g[67][KK];
  if (t < KK) gi[t] = gidx[bs*KK + t];
  __syncthreads();
  for (int idx = t; idx < 67*KK; idx += 128) {
    int i = idx >> 4, k = idx & 15;
    float v;
    if (i < 64) v = points[(b*64+i)*NN + gi[k]];
    else {
      int c = i - 64;
      v = xyz[(b*3+c)*NN + gi[k]] - newxyz[(b*3+c)*SS + s];
    }
    g[i][k] = v;
  }
  __syncthreads();
  float acc[KK];
  #pragma unroll
  for (int k = 0; k < KK; ++k) acc[k] = 0.0f;
  const float* wrow = td_w + t*67;
  for (int i = 0; i < 67; ++i) {
    float w = wrow[i];
    #pragma unroll
    for (int k = 0; k < KK; ++k) acc[k] = fmaf(w, g[i][k], acc[k]);
  }
  float bias = td_b[t];
  float mx = -1e30f, s1 = 0.f, s2 = 0.f;
  #pragma unroll
  for (int k = 0; k < KK; ++k) {
    float y = acc[k] + bias;
    mx = fmaxf(mx, y);
    s1 += y;
    s2 = fmaf(y, y, s2);
  }
  ymax[bs*128 + t] = mx;             // coalesced
  psum[bs*128 + t] = s1;             // coalesced
  psq [bs*128 + t] = s2;             // coalesced
}

// stage 1: 128 blocks x 256 thr; each block reduces 64 bs-rows coalesced
__global__ __launch_bounds__(256) void bn_partial(
    const float* __restrict__ psum, const float* __restrict__ psq,
    float* __restrict__ part1, float* __restrict__ part2)
{
  const int blk = blockIdx.x, t = threadIdx.x;
  const int c = t & 127, half = t >> 7;
  const float* ps = psum + (blk*64 + half*32)*128;
  const float* pq = psq  + (blk*64 + half*32)*128;
  float s1 = 0.f, s2 = 0.f;
  for (int r = 0; r < 32; ++r) { s1 += ps[r*128 + c]; s2 += pq[r*128 + c]; }
  __shared__ float sh1[256], sh2[256];
  sh1[t] = s1; sh2[t] = s2;
  __syncthreads();
  if (t < 128) {
    part1[blk*128 + t] = sh1[t] + sh1[t+128];
    part2[blk*128 + t] = sh2[t] + sh2[t+128];
  }
}

// stage 2: 1 block x 128 thr
__global__ __launch_bounds__(128) void bn_final(
    const float* __restrict__ part1, const float* __restrict__ part2,
    const float* __restrict__ gamma, const float* __restrict__ beta,
    float* __restrict__ scale, float* __restrict__ bias)
{
  const int o = threadIdx.x;
  float s1 = 0.f, s2 = 0.f;
  for (int j = 0; j < 128; ++j) { s1 += part1[j*128+o]; s2 += part2[j*128+o]; }
  const float n = (float)(BB*SS*KK);
  float mean = s1/n;
  float var  = s2/n - mean*mean;
  float sc = gamma[o] / sqrtf(var + 1e-5f);
  scale[o] = sc;
  bias[o]  = beta[o] - mean*sc;
}

// ---------------- r1_first: fused td_final + r1 (i=0) ----------------
__global__ __launch_bounds__(128) void r1_first(
    const float* __restrict__ ymax,   // [B*S,128]
    const float* __restrict__ scale, const float* __restrict__ bias,
    const float* __restrict__ bw, const float* __restrict__ bb,   // [32,128],[32]
    const float* __restrict__ qw,                                 // [96,32]
    float* __restrict__ pts,          // [B*S,128] (written here)
    float* __restrict__ qkv)
{
  const int bs = blockIdx.x;
  const int t = threadIdx.x;
  __shared__ float pcol[128];
  __shared__ float p[32];
  float v = fmaxf(fmaf(ymax[bs*128 + t], scale[t], bias[t]), 0.0f);
  pts[bs*128 + t] = v;               // materialize pts for r2's residual +=
  pcol[t] = v;
  __syncthreads();
  if (t < 32) {
    float acc = 0.f;
    const float* w = bw + t*128;
    for (int j = 0; j < 128; ++j) acc = fmaf(w[j], pcol[j], acc);
    p[t] = acc + bb[t];
  }
  __syncthreads();
  if (t < 96) {
    float acc = 0.f;
    const float* w = qw + t*32;
    #pragma unroll
    for (int j = 0; j < 32; ++j) acc = fmaf(w[j], p[j], acc);
    qkv[bs*96 + t] = acc;            // coalesced
  }
}

// ---------------- Res block part 1 (pts [B*S,128], qkv [B*S,96]) ----------------
__global__ __launch_bounds__(128) void r1_kernel(
    const float* __restrict__ pts,
    const float* __restrict__ bw, const float* __restrict__ bb,   // [32,128],[32]
    const float* __restrict__ qw,                                 // [96,32]
    float* __restrict__ qkv)
{
  const int bs = blockIdx.x;
  const int t = threadIdx.x;
  __shared__ float pcol[128];
  __shared__ float p[32];
  pcol[t] = pts[bs*128 + t];           // coalesced
  __syncthreads();
  if (t < 32) {
    float acc = 0.f;
    const float* w = bw + t*128;
    for (int j = 0; j < 128; ++j) acc = fmaf(w[j], pcol[j], acc);
    p[t] = acc + bb[t];
  }
  __syncthreads();
  if (t < 96) {
    float acc = 0.f;
    const float* w = qw + t*32;
    #pragma unroll
    for (int j = 0; j < 32; ++j) acc = fmaf(w[j], p[j], acc);
    qkv[bs*96 + t] = acc;              // coalesced
  }
}

// ---------------- Res block part 2 (qkv [B*S,96], pts [B*S,128]) ----------------
__global__ __launch_bounds__(128) void r2_kernel(
    const float* __restrict__ qkv,
    const float* __restrict__ newxyz, // [B,3,S]
    const int* __restrict__ sgidx,    // [B,S,K]
    const float* __restrict__ pw1, const float* __restrict__ pb1,  // [64,3],[64]
    const float* __restrict__ pw2, const float* __restrict__ pb2,  // [32,64],[32]
    const float* __restrict__ aw1, const float* __restrict__ ab1,  // [128,32],[128]
    const float* __restrict__ aw2, const float* __restrict__ ab2,  // [32,128],[32]
    const float* __restrict__ fw,  const float* __restrict__ fb,   // [128,32],[128]
    float* __restrict__ pts)          // [B*S,128]  (+=)
{
  const int bs = blockIdx.x;
  const int b = bs >> 11, s = bs & (SS-1);
  const int t = threadIdx.x;
  __shared__ int sgi[KK];
  __shared__ float qv[32];
  __shared__ float kn[32*17], vn[32*17];   // stride 17: conflict-free
  __shared__ float gx[3*KK];
  __shared__ float h1[64*KK];
  __shared__ float x2[32*KK];
  __shared__ float a1[128*17];             // stride 17: kills 16-way write conflicts
  __shared__ float simb[32*KK];
  __shared__ float agg[32];
  if (t < KK) sgi[t] = sgidx[bs*KK + t];
  __syncthreads();
  if (t < 32) qv[t] = qkv[bs*96 + t];
  // c-major gather: each wave reads 2 neighbor rows x 32 consecutive floats (coalesced)
  for (int idx = t; idx < 32*KK; idx += 128) {
    int k = idx >> 5, c = idx & 31;
    int base = (b*SS + sgi[k])*96;
    kn[c*17+k] = qkv[base + 32 + c];
    vn[c*17+k] = qkv[base + 64 + c];
  }
  if (t < 3*KK) {
    int c = t >> 4, k = t & 15;
    gx[t] = newxyz[(b*3+c)*SS + s] - newxyz[(b*3+c)*SS + sgi[k]];
  }
  __syncthreads();
  for (int idx = t; idx < 64*KK; idx += 128) {
    int c = idx >> 4, k = idx & 15;
    float acc = 0.f;
    #pragma unroll
    for (int j = 0; j < 3; ++j) acc = fmaf(pw1[c*3+j], gx[j*KK+k], acc);
    h1[idx] = fmaxf(acc + pb1[c], 0.0f);
  }
  __syncthreads();
  for (int idx = t; idx < 32*KK; idx += 128) {
    int c = idx >> 4, k = idx & 15;
    float acc = 0.f;
    const float* w = pw2 + c*64;
    for (int j = 0; j < 64; ++j) acc = fmaf(w[j], h1[j*KK+k], acc);
    float r = acc + pb2[c];
    x2[idx] = (qv[c] - kn[c*17+k]) + r;   // qk_rel + rel
    vn[c*17+k] = vn[c*17+k] + r;          // v + rel
  }
  __syncthreads();
  {
    float acc[KK];
    #pragma unroll
    for (int k = 0; k < KK; ++k) acc[k] = 0.f;
    const float* w = aw1 + t*32;
    for (int j = 0; j < 32; ++j) {
      float wv = w[j];
      #pragma unroll
      for (int k = 0; k < KK; ++k) acc[k] = fmaf(wv, x2[j*KK+k], acc[k]);
    }
    float bv = ab1[t];
    #pragma unroll
    for (int k = 0; k < KK; ++k) a1[t*17+k] = fmaxf(acc[k] + bv, 0.0f);
  }
  __syncthreads();
  for (int idx = t; idx < 32*KK; idx += 128) {
    int c = idx >> 4, k = idx & 15;
    float acc = 0.f;
    const float* w = aw2 + c*128;
    for (int j = 0; j < 128; ++j) acc = fmaf(w[j], a1[j*17+k], acc);
    simb[idx] = acc + ab2[c];
  }
  __syncthreads();
  if (t < 32) {
    float m = -1e30f;
    #pragma unroll
    for (int k = 0; k < KK; ++k) m = fmaxf(m, simb[t*KK+k]);
    float sum = 0.f;
    float e[KK];
    #pragma unroll
    for (int k = 0; k < KK; ++k) { e[k] = __expf(simb[t*KK+k] - m); sum += e[k]; }
    float inv = 1.0f / sum;
    float a = 0.f;
    #pragma unroll
    for (int k = 0; k < KK; ++k) a = fmaf(e[k]*inv, vn[t*17+k], a);
    agg[t] = a;
  }
  __syncthreads();
  {
    float acc = 0.f;
    const float* w = fw + t*32;
    #pragma unroll
    for (int j = 0; j < 32; ++j) acc = fmaf(w[j], agg[j], acc);
    pts[bs*128 + t] += acc + fb[t];    // coalesced
  }
}

// transpose pts [B,S,128] -> out [B,128,S]
__global__ __launch_bounds__(256) void transpose_out(
    const float* __restrict__ pts, float* __restrict__ out)
{
  __shared__ float tile[32][33];
  const int b = blockIdx.z;
  const int s0 = blockIdx.x*32, c0 = blockIdx.y*32;
  const int x = threadIdx.x, y = threadIdx.y;   // 32 x 8
  #pragma unroll
  for (int i = y; i < 32; i += 8)
    tile[i][x] = pts[(b*SS + s0+i)*128 + c0+x];
  __syncthreads();
  #pragma unroll
  for (int i = y; i < 32; i += 8)
    out[(b*128 + c0+i)*SS + s0 + x] = tile[x][i];
}

extern "C" void kernel_launch(void* const* d_in, const int* in_sizes, int n_in,
                              void* d_out, int out_size, void* d_ws, size_t ws_size,
                              hipStream_t stream) {
  const float* xyz      = (const float*)d_in[0];
  const float* points   = (const float*)d_in[1];
  const float* td_w     = (const float*)d_in[2];
  const float* td_b     = (const float*)d_in[3];
  const float* td_gamma = (const float*)d_in[4];
  const float* td_beta  = (const float*)d_in[5];
  const float* bw  = (const float*)d_in[6];
  const float* bb  = (const float*)d_in[7];
  const float* qw  = (const float*)d_in[8];
  const float* pw1 = (const float*)d_in[9];
  const float* pb1 = (const float*)d_in[10];
  const float* pw2 = (const float*)d_in[11];
  const float* pb2 = (const float*)d_in[12];
  const float* aw1 = (const float*)d_in[13];
  const float* ab1 = (const float*)d_in[14];
  const float* aw2 = (const float*)d_in[15];
  const float* ab2 = (const float*)d_in[16];
  const float* fw  = (const float*)d_in[17];
  const float* fb  = (const float*)d_in[18];
  float* out = (float*)d_out;
  float* out_newxyz = out;                 // [B,3,S]
  float* out_pts    = out + BB*3*SS;       // [B,128,S]

  char* w = (char*)d_ws;
  float* nxt    = (float*)w; w += BB*SS*3*sizeof(float);
  int*   gidx   = (int*)w;   w += BB*SS*KK*sizeof(int);
  int*   sgidx  = (int*)w;   w += BB*SS*KK*sizeof(int);
  float* ymax   = (float*)w; w += BB*128*SS*sizeof(float);
  float* psum   = (float*)w; w += 128*BB*SS*sizeof(float);
  float* psq    = (float*)w; w += 128*BB*SS*sizeof(float);
  float* part1  = (float*)w; w += 128*128*sizeof(float);
  float* part2  = (float*)w; w += 128*128*sizeof(float);
  float* bnscale= (float*)w; w += 256*sizeof(float);
  float* bnbias = (float*)w; w += 256*sizeof(float);
  float* pts    = (float*)w; w += BB*128*SS*sizeof(float);
  float* qkv    = (float*)w; w += BB*96*SS*sizeof(float);

  fps_kernel<<<BB, FTH, 0, stream>>>(xyz, out_newxyz, nxt);
  knn_kernel<<<2*BB*(SS/64), KTH, 0, stream>>>(nxt, xyz, out_newxyz, gidx, sgidx);
  td_kernel<<<BB*SS, 128, 0, stream>>>(points, xyz, out_newxyz, gidx, td_w, td_b, ymax, psum, psq);
  bn_partial<<<128, 256, 0, stream>>>(psum, psq, part1, part2);
  bn_final<<<1, 128, 0, stream>>>(part1, part2, td_gamma, td_beta, bnscale, bnbias);
  // i = 0: r1 fused with td_final (writes pts from ymax)
  r1_first<<<BB*SS, 128, 0, stream>>>(ymax, bnscale, bnbias, bw, bb, qw, pts, qkv);
  r2_kernel<<<BB*SS, 128, 0, stream>>>(qkv, out_newxyz, sgidx,
      pw1, pb1, pw2, pb2, aw1, ab1, aw2, ab2, fw, fb, pts);
  // i = 1
  r1_kernel<<<BB*SS, 128, 0, stream>>>(pts, bw + 32*128, bb + 32, qw + 96*32, qkv);
  r2_kernel<<<BB*SS, 128, 0, stream>>>(qkv, out_newxyz, sgidx,
      pw1 + 64*3, pb1 + 64, pw2 + 32*64, pb2 + 32,
      aw1 + 128*32, ab1 + 128, aw2 + 32*128, ab2 + 32,
      fw + 128*32, fb + 128, pts);
  dim3 tg(SS/32, 128/32, BB), tb(32, 8);
  transpose_out<<<tg, tb, 0, stream>>>(pts, out_pts);
}

// Round 14
// 2677.316 us; speedup vs baseline: 1.0979x; 1.0979x over previous
//
#include <hip/hip_runtime.h>

#define BB 4
#define NN 8192
#define SS 2048
#define KK 16

typedef float v2f __attribute__((ext_vector_type(2)));

// ---------------- FPS (R10 verbatim — measured best 1822us): 512 thr, 2 barriers, u32 atomicMin ----------------
#define FTH 512
#define FPT (NN/FTH)  // 16 points per thread
__global__ __launch_bounds__(FTH, 1) void fps_kernel(
    const float* __restrict__ xyz,   // [B,3,N]
    float* __restrict__ out_newxyz,  // [B,3,S]
    float* __restrict__ nxt)         // [B,S,3]
{
  #pragma clang fp contract(off)
  const int b = blockIdx.x;
  const int tid = threadIdx.x;
  const int wave = tid >> 6;
  const int lane = tid & 63;
  const float* xb = xyz + b*3*NN;
  __shared__ float sx[NN], sy[NN], sz[NN];          // 96 KB xyz copy (centroid bcast + epilogue)
  __shared__ __align__(16) float smax[8];
  __shared__ unsigned gidx_slot[2];
  __shared__ int smi[SS];                           // winning-index history (8 KB)
  v2f px[FPT/2], py[FPT/2], pz[FPT/2], dist[FPT/2];
  #pragma unroll
  for (int j = 0; j < FPT; ++j) {
    int i = tid + j*FTH;
    float x = xb[i], y = xb[NN+i], z = xb[2*NN+i];
    asm volatile("" : "+v"(x), "+v"(y), "+v"(z));   // pin: forbid remat/reload
    ((float*)px)[j] = x; ((float*)py)[j] = y; ((float*)pz)[j] = z;
    ((float*)dist)[j] = 1e10f;
  }
  #pragma unroll
  for (int j = 0; j < FPT; ++j) {
    int i = tid + j*FTH;
    sx[i] = ((float*)px)[j]; sy[i] = ((float*)py)[j]; sz[i] = ((float*)pz)[j];
  }
  if (tid == 0) { smi[0] = 0; gidx_slot[0] = 0xFFFFFFFFu; gidx_slot[1] = 0xFFFFFFFFu; }
  float cx = xb[0], cy = xb[NN], cz = xb[2*NN];
  __syncthreads();
  for (int it = 1; it < SS; ++it) {
    const int buf = it & 1;
    v2f cx2 = {cx, cx}, cy2 = {cy, cy}, cz2 = {cz, cz};
    v2f vmax = {-1.0f, -1.0f};
    #pragma unroll
    for (int j = 0; j < FPT/2; ++j) {
      // packed fp32: per-element arithmetic identical to scalar (contract off)
      v2f dx = px[j] - cx2, dy = py[j] - cy2, dz = pz[j] - cz2;
      v2f d = dx*dx + dy*dy;
      d = d + dz*dz;
      v2f nd = __builtin_elementwise_min(dist[j], d);
      dist[j] = nd;
      vmax = __builtin_elementwise_max(vmax, nd);
    }
    float mloc = fmaxf(vmax.x, vmax.y);
    // wave-level value-only max via DPP (identity 0 fill is safe: values >= 0)
    float m = mloc;
    #define FPS_DPP(ctrl) { \
      float s = __int_as_float(__builtin_amdgcn_update_dpp(0, __float_as_int(m), ctrl, 0xf, 0xf, true)); \
      m = fmaxf(m, s); }
    FPS_DPP(0x111)  // row_shr:1
    FPS_DPP(0x112)  // row_shr:2
    FPS_DPP(0x114)  // row_shr:4
    FPS_DPP(0x118)  // row_shr:8
    FPS_DPP(0x142)  // row_bcast:15
    FPS_DPP(0x143)  // row_bcast:31
    #undef FPS_DPP
    if (lane == 63) smax[wave] = m;
    __syncthreads();
    if (tid == 0) gidx_slot[1 - buf] = 0xFFFFFFFFu;   // reset buffer for next iteration
    float4 s0 = ((const float4*)smax)[0];
    float4 s1 = ((const float4*)smax)[1];
    float M = fmaxf(fmaxf(fmaxf(s0.x, s0.y), fmaxf(s0.z, s0.w)),
                    fmaxf(fmaxf(s1.x, s1.y), fmaxf(s1.z, s1.w)));
    if (mloc == M) {
      // exact bit-equality: max propagates one of its inputs.
      // descending j, .y before .x -> smallest matching index in this thread
      int idx = 0x7FFFFFFF;
      #pragma unroll
      for (int j = FPT/2 - 1; j >= 0; --j) {
        if (dist[j].y == M) idx = tid + (2*j+1)*FTH;
        if (dist[j].x == M) idx = tid + (2*j)*FTH;
      }
      atomicMin(&gidx_slot[buf], (unsigned)idx);      // ties -> smallest index (np argmax)
    }
    __syncthreads();
    int mi = (int)gidx_slot[buf];
    if (tid == 0) smi[it] = mi;
    cx = sx[mi]; cy = sy[mi]; cz = sz[mi];
  }
  __syncthreads();
  // epilogue: write sampled coords coalesced, outside the serial loop
  for (int it = tid; it < SS; it += FTH) {
    int mi = smi[it];
    float x = sx[mi], y = sy[mi], z = sz[mi];
    out_newxyz[(b*3+0)*SS + it] = x;
    out_newxyz[(b*3+1)*SS + it] = y;
    out_newxyz[(b*3+2)*SS + it] = z;
    nxt[(b*SS+it)*3+0] = x; nxt[(b*SS+it)*3+1] = y; nxt[(b*SS+it)*3+2] = z;
  }
}

// ---------------- transpose points [B,64,N] -> ptst [B,N,64] (coalesced both sides) ----------------
__global__ __launch_bounds__(256) void transpose_pts(
    const float* __restrict__ p, float* __restrict__ o)
{
  __shared__ float tile[32][33];
  const int b = blockIdx.z;
  const int n0 = blockIdx.x*32, c0 = blockIdx.y*32;
  const int x = threadIdx.x, y = threadIdx.y;   // 32 x 8
  #pragma unroll
  for (int i = y; i < 32; i += 8)
    tile[i][x] = p[(b*64 + c0+i)*NN + n0+x];
  __syncthreads();
  #pragma unroll
  for (int i = y; i < 32; i += 8)
    o[(b*NN + n0+i)*64 + c0+x] = tile[x][i];
}

// ---------------- KNN fused, 512 thr = 8 waves; each wave scans 1/8; 8-way stable merge ----------------
#define TILE 2048
#define KTH 512
__global__ __launch_bounds__(KTH) void knn_kernel(
    const float* __restrict__ query_t, // [B,S,3]
    const float* __restrict__ cand1,   // [B,3,NN]
    const float* __restrict__ cand2,   // [B,3,SS]
    int* __restrict__ out1,            // [B,S,K]
    int* __restrict__ out2)            // [B,S,K]
{
  #pragma clang fp contract(off)
  __shared__ float4 sc[TILE];            // 32 KB
  __shared__ float  smd[8*64*17];        // per-wave top-16 dists (pad 17) ~34.8 KB
  __shared__ int    smj[8*64*17];        // per-wave top-16 idxs
  const int blocksPerB = SS/64;          // 32
  const int half = blockIdx.x >> 7;      // 0: vs xyz, 1: self
  const int blk = blockIdx.x & 127;
  const float* cand = half ? cand2 : cand1;
  const int Nc = half ? SS : NN;
  int* outidx = half ? out2 : out1;
  const int b = blk / blocksPerB;
  const int q0 = (blk % blocksPerB)*64;
  const int wave = threadIdx.x >> 6, lane = threadIdx.x & 63;
  const int s = q0 + lane;
  const float qx = query_t[(b*SS+s)*3+0];
  const float qy = query_t[(b*SS+s)*3+1];
  const float qz = query_t[(b*SS+s)*3+2];
  float sq = qx*qx + qy*qy; sq = sq + qz*qz;
  float d16[16]; int i16[16];
  #pragma unroll
  for (int j = 0; j < 16; ++j) { d16[j] = 1e30f; i16[j] = 0x7FFFFFFF; }
  const float* cb = cand + b*3*Nc;
  const int QL = TILE/8;                 // 256 candidates per wave per tile
  for (int base = 0; base < Nc; base += TILE) {
    __syncthreads();
    for (int j = threadIdx.x; j < TILE; j += KTH) {
      float x = cb[base+j], y = cb[Nc+base+j], z = cb[2*Nc+base+j];
      float pp = x*x + y*y; pp = pp + z*z;
      sc[j] = make_float4(x, y, z, pp);
    }
    __syncthreads();
    const int lo = wave*QL, hi = lo + QL;
    for (int j = lo; j < hi; ++j) {
      float4 c = sc[j];
      float qp = qx*c.x + qy*c.y; qp = qp + qz*c.z;
      float d2 = (sq + c.w) - 2.0f*qp;
      if (d2 < d16[15]) {
        d16[15] = d2; i16[15] = base + j;
        #pragma unroll
        for (int t = 15; t > 0; --t) {
          if (d16[t] < d16[t-1]) {
            float td = d16[t]; d16[t] = d16[t-1]; d16[t-1] = td;
            int   ti = i16[t]; i16[t] = i16[t-1]; i16[t-1] = ti;
          }
        }
      }
    }
  }
  const int off = (wave*64 + lane)*17;
  #pragma unroll
  for (int j = 0; j < 16; ++j) { smd[off+j] = d16[j]; smj[off+j] = i16[j]; }
  __syncthreads();
  if (wave == 0) {
    // 8-way stable merge: tie-break on smaller index = stable lax.top_k semantics
    int p[8] = {0,0,0,0,0,0,0,0};
    for (int o = 0; o < 16; ++o) {
      float bd = 3e38f; int bi = 0x7FFFFFFF, bw = 0;
      #pragma unroll
      for (int w = 0; w < 8; ++w) {
        float d = smd[(w*64+lane)*17 + p[w]];
        int   i = smj[(w*64+lane)*17 + p[w]];
        if (d < bd || (d == bd && i < bi)) { bd = d; bi = i; bw = w; }
      }
      p[bw]++;
      outidx[(b*SS+s)*KK + o] = bi;
    }
  }
}

// ---------------- Transition-down conv + stats + max over K (ptst gather, coalesced) ----------------
__global__ __launch_bounds__(128) void td_kernel(
    const float* __restrict__ ptst,    // [B,N,64] point-major
    const float* __restrict__ xyz,     // [B,3,N]
    const float* __restrict__ newxyz,  // [B,3,S]
    const int* __restrict__ gidx,      // [B,S,K]
    const float* __restrict__ td_w,    // [128,67]
    const float* __restrict__ td_b,    // [128]
    float* __restrict__ ymax,          // [B*S,128]
    float* __restrict__ psum,          // [B*S,128]
    float* __restrict__ psq)
{
  const int bs = blockIdx.x;
  const int b = bs >> 11, s = bs & (SS-1);
  const int t = threadIdx.x;
  __shared__ int gi[KK];
  __shared__ float g[67*17];           // stride 17: conflict-free writes
  if (t < KK) gi[t] = gidx[bs*KK + t];
  __syncthreads();
  // features 0..63: per neighbor, 64 consecutive floats (coalesced 256B rows)
  #pragma unroll
  for (int base = 0; base < 1024; base += 128) {
    int idx = base + t;
    int i = idx & 63, k = idx >> 6;
    g[i*17 + k] = ptst[(b*NN + gi[k])*64 + i];
  }
  // xyz channels 64..66 (48 scattered reads)
  if (t < 48) {
    int c = t >> 4, k = t & 15;
    g[(64+c)*17 + k] = xyz[(b*3+c)*NN + gi[k]] - newxyz[(b*3+c)*SS + s];
  }
  __syncthreads();
  float acc[KK];
  #pragma unroll
  for (int k = 0; k < KK; ++k) acc[k] = 0.0f;
  const float* wrow = td_w + t*67;
  for (int i = 0; i < 67; ++i) {
    float w = wrow[i];
    #pragma unroll
    for (int k = 0; k < KK; ++k) acc[k] = fmaf(w, g[i*17 + k], acc[k]);
  }
  float bias = td_b[t];
  float mx = -1e30f, s1 = 0.f, s2 = 0.f;
  #pragma unroll
  for (int k = 0; k < KK; ++k) {
    float y = acc[k] + bias;
    mx = fmaxf(mx, y);
    s1 += y;
    s2 = fmaf(y, y, s2);
  }
  ymax[bs*128 + t] = mx;             // coalesced
  psum[bs*128 + t] = s1;             // coalesced
  psq [bs*128 + t] = s2;             // coalesced
}

// stage 1: 128 blocks x 256 thr; each block reduces 64 bs-rows coalesced
__global__ __launch_bounds__(256) void bn_partial(
    const float* __restrict__ psum, const float* __restrict__ psq,
    float* __restrict__ part1, float* __restrict__ part2)
{
  const int blk = blockIdx.x, t = threadIdx.x;
  const int c = t & 127, half = t >> 7;
  const float* ps = psum + (blk*64 + half*32)*128;
  const float* pq = psq  + (blk*64 + half*32)*128;
  float s1 = 0.f, s2 = 0.f;
  for (int r = 0; r < 32; ++r) { s1 += ps[r*128 + c]; s2 += pq[r*128 + c]; }
  __shared__ float sh1[256], sh2[256];
  sh1[t] = s1; sh2[t] = s2;
  __syncthreads();
  if (t < 128) {
    part1[blk*128 + t] = sh1[t] + sh1[t+128];
    part2[blk*128 + t] = sh2[t] + sh2[t+128];
  }
}

// stage 2: 1 block x 128 thr
__global__ __launch_bounds__(128) void bn_final(
    const float* __restrict__ part1, const float* __restrict__ part2,
    const float* __restrict__ gamma, const float* __restrict__ beta,
    float* __restrict__ scale, float* __restrict__ bias)
{
  const int o = threadIdx.x;
  float s1 = 0.f, s2 = 0.f;
  for (int j = 0; j < 128; ++j) { s1 += part1[j*128+o]; s2 += part2[j*128+o]; }
  const float n = (float)(BB*SS*KK);
  float mean = s1/n;
  float var  = s2/n - mean*mean;
  float sc = gamma[o] / sqrtf(var + 1e-5f);
  scale[o] = sc;
  bias[o]  = beta[o] - mean*sc;
}

// ---------------- r1_first: fused td_final + r1 (i=0) ----------------
__global__ __launch_bounds__(128) void r1_first(
    const float* __restrict__ ymax,   // [B*S,128]
    const float* __restrict__ scale, const float* __restrict__ bias,
    const float* __restrict__ bw, const float* __restrict__ bb,   // [32,128],[32]
    const float* __restrict__ qw,                                 // [96,32]
    float* __restrict__ pts,          // [B*S,128] (written here)
    float* __restrict__ qkv)
{
  const int bs = blockIdx.x;
  const int t = threadIdx.x;
  __shared__ float pcol[128];
  __shared__ float p[32];
  float v = fmaxf(fmaf(ymax[bs*128 + t], scale[t], bias[t]), 0.0f);
  pts[bs*128 + t] = v;               // materialize pts for r2's residual +=
  pcol[t] = v;
  __syncthreads();
  if (t < 32) {
    float acc = 0.f;
    const float* w = bw + t*128;
    for (int j = 0; j < 128; ++j) acc = fmaf(w[j], pcol[j], acc);
    p[t] = acc + bb[t];
  }
  __syncthreads();
  if (t < 96) {
    float acc = 0.f;
    const float* w = qw + t*32;
    #pragma unroll
    for (int j = 0; j < 32; ++j) acc = fmaf(w[j], p[j], acc);
    qkv[bs*96 + t] = acc;            // coalesced
  }
}

// ---------------- Res block part 1 (pts [B*S,128], qkv [B*S,96]) ----------------
__global__ __launch_bounds__(128) void r1_kernel(
    const float* __restrict__ pts,
    const float* __restrict__ bw, const float* __restrict__ bb,   // [32,128],[32]
    const float* __restrict__ qw,                                 // [96,32]
    float* __restrict__ qkv)
{
  const int bs = blockIdx.x;
  const int t = threadIdx.x;
  __shared__ float pcol[128];
  __shared__ float p[32];
  pcol[t] = pts[bs*128 + t];           // coalesced
  __syncthreads();
  if (t < 32) {
    float acc = 0.f;
    const float* w = bw + t*128;
    for (int j = 0; j < 128; ++j) acc = fmaf(w[j], pcol[j], acc);
    p[t] = acc + bb[t];
  }
  __syncthreads();
  if (t < 96) {
    float acc = 0.f;
    const float* w = qw + t*32;
    #pragma unroll
    for (int j = 0; j < 32; ++j) acc = fmaf(w[j], p[j], acc);
    qkv[bs*96 + t] = acc;              // coalesced
  }
}

// ---------------- Res block part 2 (qkv [B*S,96], pts [B*S,128]) ----------------
__global__ __launch_bounds__(128) void r2_kernel(
    const float* __restrict__ qkv,
    const float* __restrict__ newxyz, // [B,3,S]
    const int* __restrict__ sgidx,    // [B,S,K]
    const float* __restrict__ pw1, const float* __restrict__ pb1,  // [64,3],[64]
    const float* __restrict__ pw2, const float* __restrict__ pb2,  // [32,64],[32]
    const float* __restrict__ aw1, const float* __restrict__ ab1,  // [128,32],[128]
    const float* __restrict__ aw2, const float* __restrict__ ab2,  // [32,128],[32]
    const float* __restrict__ fw,  const float* __restrict__ fb,   // [128,32],[128]
    float* __restrict__ pts)          // [B*S,128]  (+=)
{
  const int bs = blockIdx.x;
  const int b = bs >> 11, s = bs & (SS-1);
  const int t = threadIdx.x;
  __shared__ int sgi[KK];
  __shared__ float qv[32];
  __shared__ float kn[32*17], vn[32*17];   // stride 17: conflict-free
  __shared__ float gx[3*KK];
  __shared__ float h1[64*KK];
  __shared__ float x2[32*KK];
  __shared__ float a1[128*17];             // stride 17: kills 16-way write conflicts
  __shared__ float simb[32*KK];
  __shared__ float agg[32];
  if (t < KK) sgi[t] = sgidx[bs*KK + t];
  __syncthreads();
  if (t < 32) qv[t] = qkv[bs*96 + t];
  // c-major gather: each wave reads 2 neighbor rows x 32 consecutive floats (coalesced)
  for (int idx = t; idx < 32*KK; idx += 128) {
    int k = idx >> 5, c = idx & 31;
    int base = (b*SS + sgi[k])*96;
    kn[c*17+k] = qkv[base + 32 + c];
    vn[c*17+k] = qkv[base + 64 + c];
  }
  if (t < 3*KK) {
    int c = t >> 4, k = t & 15;
    gx[t] = newxyz[(b*3+c)*SS + s] - newxyz[(b*3+c)*SS + sgi[k]];
  }
  __syncthreads();
  for (int idx = t; idx < 64*KK; idx += 128) {
    int c = idx >> 4, k = idx & 15;
    float acc = 0.f;
    #pragma unroll
    for (int j = 0; j < 3; ++j) acc = fmaf(pw1[c*3+j], gx[j*KK+k], acc);
    h1[idx] = fmaxf(acc + pb1[c], 0.0f);
  }
  __syncthreads();
  for (int idx = t; idx < 32*KK; idx += 128) {
    int c = idx >> 4, k = idx & 15;
    float acc = 0.f;
    const float* w = pw2 + c*64;
    for (int j = 0; j < 64; ++j) acc = fmaf(w[j], h1[j*KK+k], acc);
    float r = acc + pb2[c];
    x2[idx] = (qv[c] - kn[c*17+k]) + r;   // qk_rel + rel
    vn[c*17+k] = vn[c*17+k] + r;          // v + rel
  }
  __syncthreads();
  {
    float acc[KK];
    #pragma unroll
    for (int k = 0; k < KK; ++k) acc[k] = 0.f;
    const float* w = aw1 + t*32;
    for (int j = 0; j < 32; ++j) {
      float wv = w[j];
      #pragma unroll
      for (int k = 0; k < KK; ++k) acc[k] = fmaf(wv, x2[j*KK+k], acc[k]);
    }
    float bv = ab1[t];
    #pragma unroll
    for (int k = 0; k < KK; ++k) a1[t*17+k] = fmaxf(acc[k] + bv, 0.0f);
  }
  __syncthreads();
  for (int idx = t; idx < 32*KK; idx += 128) {
    int c = idx >> 4, k = idx & 15;
    float acc = 0.f;
    const float* w = aw2 + c*128;
    for (int j = 0; j < 128; ++j) acc = fmaf(w[j], a1[j*17+k], acc);
    simb[idx] = acc + ab2[c];
  }
  __syncthreads();
  if (t < 32) {
    float m = -1e30f;
    #pragma unroll
    for (int k = 0; k < KK; ++k) m = fmaxf(m, simb[t*KK+k]);
    float sum = 0.f;
    float e[KK];
    #pragma unroll
    for (int k = 0; k < KK; ++k) { e[k] = __expf(simb[t*KK+k] - m); sum += e[k]; }
    float inv = 1.0f / sum;
    float a = 0.f;
    #pragma unroll
    for (int k = 0; k < KK; ++k) a = fmaf(e[k]*inv, vn[t*17+k], a);
    agg[t] = a;
  }
  __syncthreads();
  {
    float acc = 0.f;
    const float* w = fw + t*32;
    #pragma unroll
    for (int j = 0; j < 32; ++j) acc = fmaf(w[j], agg[j], acc);
    pts[bs*128 + t] += acc + fb[t];    // coalesced
  }
}

// transpose pts [B,S,128] -> out [B,128,S]
__global__ __launch_bounds__(256) void transpose_out(
    const float* __restrict__ pts, float* __restrict__ out)
{
  __shared__ float tile[32][33];
  const int b = blockIdx.z;
  const int s0 = blockIdx.x*32, c0 = blockIdx.y*32;
  const int x = threadIdx.x, y = threadIdx.y;   // 32 x 8
  #pragma unroll
  for (int i = y; i < 32; i += 8)
    tile[i][x] = pts[(b*SS + s0+i)*128 + c0+x];
  __syncthreads();
  #pragma unroll
  for (int i = y; i < 32; i += 8)
    out[(b*128 + c0+i)*SS + s0 + x] = tile[x][i];
}

extern "C" void kernel_launch(void* const* d_in, const int* in_sizes, int n_in,
                              void* d_out, int out_size, void* d_ws, size_t ws_size,
                              hipStream_t stream) {
  const float* xyz      = (const float*)d_in[0];
  const float* points   = (const float*)d_in[1];
  const float* td_w     = (const float*)d_in[2];
  const float* td_b     = (const float*)d_in[3];
  const float* td_gamma = (const float*)d_in[4];
  const float* td_beta  = (const float*)d_in[5];
  const float* bw  = (const float*)d_in[6];
  const float* bb  = (const float*)d_in[7];
  const float* qw  = (const float*)d_in[8];
  const float* pw1 = (const float*)d_in[9];
  const float* pb1 = (const float*)d_in[10];
  const float* pw2 = (const float*)d_in[11];
  const float* pb2 = (const float*)d_in[12];
  const float* aw1 = (const float*)d_in[13];
  const float* ab1 = (const float*)d_in[14];
  const float* aw2 = (const float*)d_in[15];
  const float* ab2 = (const float*)d_in[16];
  const float* fw  = (const float*)d_in[17];
  const float* fb  = (const float*)d_in[18];
  float* out = (float*)d_out;
  float* out_newxyz = out;                 // [B,3,S]
  float* out_pts    = out + BB*3*SS;       // [B,128,S]

  char* w = (char*)d_ws;
  float* nxt    = (float*)w; w += BB*SS*3*sizeof(float);
  int*   gidx   = (int*)w;   w += BB*SS*KK*sizeof(int);
  int*   sgidx  = (int*)w;   w += BB*SS*KK*sizeof(int);
  float* ymax   = (float*)w; w += BB*128*SS*sizeof(float);
  float* psum   = (float*)w; w += 128*BB*SS*sizeof(float);
  float* psq    = (float*)w; w += 128*BB*SS*sizeof(float);
  float* part1  = (float*)w; w += 128*128*sizeof(float);
  float* part2  = (float*)w; w += 128*128*sizeof(float);
  float* bnscale= (float*)w; w += 256*sizeof(float);
  float* bnbias = (float*)w; w += 256*sizeof(float);
  float* pts    = (float*)w; w += BB*128*SS*sizeof(float);
  float* qkv    = (float*)w; w += BB*96*SS*sizeof(float);
  float* ptst   = (float*)w; w += BB*NN*64*sizeof(float);   // [B,N,64]

  fps_kernel<<<BB, FTH, 0, stream>>>(xyz, out_newxyz, nxt);
  {
    dim3 tg(NN/32, 2, BB), tb(32, 8);
    transpose_pts<<<tg, tb, 0, stream>>>(points, ptst);
  }
  knn_kernel<<<2*BB*(SS/64), KTH, 0, stream>>>(nxt, xyz, out_newxyz, gidx, sgidx);
  td_kernel<<<BB*SS, 128, 0, stream>>>(ptst, xyz, out_newxyz, gidx, td_w, td_b, ymax, psum, psq);
  bn_partial<<<128, 256, 0, stream>>>(psum, psq, part1, part2);
  bn_final<<<1, 128, 0, stream>>>(part1, part2, td_gamma, td_beta, bnscale, bnbias);
  // i = 0: r1 fused with td_final (writes pts from ymax)
  r1_first<<<BB*SS, 128, 0, stream>>>(ymax, bnscale, bnbias, bw, bb, qw, pts, qkv);
  r2_kernel<<<BB*SS, 128, 0, stream>>>(qkv, out_newxyz, sgidx,
      pw1, pb1, pw2, pb2, aw1, ab1, aw2, ab2, fw, fb, pts);
  // i = 1
  r1_kernel<<<BB*SS, 128, 0, stream>>>(pts, bw + 32*128, bb + 32, qw + 96*32, qkv);
  r2_kernel<<<BB*SS, 128, 0, stream>>>(qkv, out_newxyz, sgidx,
      pw1 + 64*3, pb1 + 64, pw2 + 32*64, pb2 + 32,
      aw1 + 128*32, ab1 + 128, aw2 + 32*128, ab2 + 32,
      fw + 128*32, fb + 128, pts);
  dim3 tg(SS/32, 128/32, BB), tb(32, 8);
  transpose_out<<<tg, tb, 0, stream>>>(pts, out_pts);
}